// Round 4
// baseline (384.351 us; speedup 1.0000x reference)
//
#include <hip/hip_runtime.h>

typedef __attribute__((ext_vector_type(8))) short short8;
typedef __attribute__((ext_vector_type(4))) float f32x4;

#define B_ 4
#define S_ 2048
#define H_ 16
#define DM 1024
#define DK 64

// 0.125 * log2(e): folds the 1/sqrt(64) score scale + exp->exp2 conversion into Q
#define QSCALE 0.18033688011112042f

__device__ __forceinline__ unsigned short f2b(float f) {
  unsigned int u = __float_as_uint(f);
  u += 0x7fff + ((u >> 16) & 1);   // RNE
  return (unsigned short)(u >> 16);
}

__device__ __forceinline__ unsigned int cvtpk_bf16(float lo, float hi) {
  unsigned int r;
  asm("v_cvt_pk_bf16_f32 %0, %1, %2" : "=v"(r) : "v"(lo), "v"(hi));
  return r;
}

// native exp2 without OCML's denorm-guard fixup (scores are |s| < ~30 here)
__device__ __forceinline__ float amd_exp2(float x) {
#if __has_builtin(__builtin_amdgcn_exp2f)
  return __builtin_amdgcn_exp2f(x);
#else
  return exp2f(x);
#endif
}

__device__ __forceinline__ void gload_lds16(const void* g, void* l) {
  __builtin_amdgcn_global_load_lds(
      (const __attribute__((address_space(1))) unsigned int*)g,
      (__attribute__((address_space(3))) unsigned int*)l, 16, 0, 0);
}

// ------- fused fp32 -> bf16 conversion for x(q,k,v) and W(q,k,v,o) -------
// one launch: blocks [0,12288) convert inputs, [12288,14336) convert weights
__global__ __launch_bounds__(256) void prep_kernel(
    const float* __restrict__ q, const float* __restrict__ k,
    const float* __restrict__ v, const float* __restrict__ wq,
    const float* __restrict__ wk, const float* __restrict__ wv,
    const float* __restrict__ wo, unsigned short* __restrict__ xb,
    unsigned short* __restrict__ wbo) {
  int bid = blockIdx.x;
  const float* src;
  unsigned short* dst;
  int i;
  if (bid < 12288) {
    int z = bid >> 12;                    // 4096 blocks per tensor
    src = (z == 0) ? q : (z == 1) ? k : v;
    dst = xb + (size_t)z * (B_ * S_ * DM);
    i = ((bid & 4095) * 256 + threadIdx.x) * 8;
  } else {
    int r = bid - 12288;
    int z = r >> 9;                       // 512 blocks per weight
    src = (z == 0) ? wq : (z == 1) ? wk : (z == 2) ? wv : wo;
    dst = wbo + (size_t)z * (DM * DM);
    i = ((r & 511) * 256 + threadIdx.x) * 8;
  }
  float4 x0 = *(const float4*)&src[i];
  float4 x1 = *(const float4*)&src[i + 4];
  alignas(16) unsigned short r8[8] = {f2b(x0.x), f2b(x0.y), f2b(x0.z), f2b(x0.w),
                                      f2b(x1.x), f2b(x1.y), f2b(x1.z), f2b(x1.w)};
  *(uint4*)&dst[i] = *(const uint4*)r8;
}

// -------- mask (int32 0/1) -> expanded packed-pair masks -----------------
// Output layout [b][g][kt][ks][mt][quad][lr] (uint4), g = q>>5 (row group),
// mt = (q>>4)&1, lr = q&15.  The uint4 {A0m,A1m,B0m,B1m} is exactly the
// halfword mask for the cvt_pk-packed P pairs in attn:
//   A0m: keys kb+quad*4+{0(lo),1(hi)}   A1m: +{2,3}     (kb = kt*64+ks*32)
//   B0m: keys kb+16+quad*4+{0,1}        B1m: +{2,3}
__global__ __launch_bounds__(256) void expand_kernel(const int* __restrict__ m,
                                                     uint4* __restrict__ out) {
  unsigned int t = blockIdx.x * 256 + threadIdx.x;   // 0 .. 2^21-1
  int lr   = t & 15;
  int quad = (t >> 4) & 3;
  int mt   = (t >> 6) & 1;
  int ks   = (t >> 7) & 1;
  int kt   = (t >> 8) & 31;
  int g    = (t >> 13) & 63;
  int b    = t >> 19;
  int q = g * 32 + mt * 16 + lr;
  int kbase = kt * 64 + ks * 32 + quad * 4;
  const int* row = m + (((size_t)(b * 2048 + q)) << 11) + kbase;
  int4 m0 = *(const int4*)row;          // keys kbase..+3
  int4 m1 = *(const int4*)(row + 16);   // keys kbase+16..+19
  uint4 r;
  r.x = (m0.x ? 0xFFFFu : 0u) | (m0.y ? 0xFFFF0000u : 0u);
  r.y = (m0.z ? 0xFFFFu : 0u) | (m0.w ? 0xFFFF0000u : 0u);
  r.z = (m1.x ? 0xFFFFu : 0u) | (m1.y ? 0xFFFF0000u : 0u);
  r.w = (m1.z ? 0xFFFFu : 0u) | (m1.w ? 0xFFFF0000u : 0u);
  out[t] = r;
}

// ---------- 128x128 bf16 GEMM, double-buffered K-staging ------------------
// LDS slot sl of row r holds global 16B-chunk sl^(r&7) (3-bit chunk swizzle).
// Schedule = the attn-proven pattern: prefetch K-tile kb+1 into the other
// buffer right after the barrier, compute kb, barrier (drains the prefetch
// via the compiler's vmcnt(0)-before-s_barrier), repeat.  One barrier per
// K-step instead of two, and the drain overlaps with compute.
// mode 1 (V^T output) routes the tile through an LDS transpose so global
// stores are coalesced dwordx4 runs along s (was a stride-2048 b16 scatter).
__device__ __forceinline__ void gemm128(
    const unsigned short* __restrict__ A, const unsigned short* __restrict__ W,
    const float* __restrict__ bias, float scale, int mode,
    unsigned short* __restrict__ outb, float* __restrict__ outf) {
  __shared__ unsigned short Sh[2][16384];  // [buf][ As(8192) | Bs(8192) ]  64 KB
  const int m0 = blockIdx.x * 128;
  const int n0 = blockIdx.y * 128;
  const int t = threadIdx.x;
  const int lane = t & 63, wave = t >> 6;
  const int lr = lane & 15, quad = lane >> 4;
  const int wm = (wave >> 1) * 64, wn = (wave & 1) * 64;
  const int srow = (lane >> 3);               // within-chunk row 0..7
  const int scol = ((lane & 7) ^ srow) * 8;   // swizzled global col chunk
  // read-side swizzled chunk offsets (shorts), per-lane invariant
  const int cs0 = (quad ^ (lr & 7)) * 8;        // ks=0
  const int cs1 = ((4 + quad) ^ (lr & 7)) * 8;  // ks=1

  const f32x4 zv = {0.f, 0.f, 0.f, 0.f};
  f32x4 acc[4][4];
#pragma unroll
  for (int mt = 0; mt < 4; mt++)
#pragma unroll
    for (int nt = 0; nt < 4; nt++) acc[mt][nt] = zv;

#define GSTAGE(KB, BUF) do {                                                   \
    int kb2 = (KB) * 64;                                                       \
    _Pragma("unroll")                                                          \
    for (int i_ = 0; i_ < 4; i_++) {                                           \
      int c_ = wave * 4 + i_;            /* chunk of 8 rows (1 KB) */          \
      int row_ = c_ * 8 + srow;                                                \
      gload_lds16(&A[(size_t)(m0 + row_) * DM + kb2 + scol], &Sh[BUF][c_ * 512]); \
      gload_lds16(&W[(size_t)(n0 + row_) * DM + kb2 + scol], &Sh[BUF][8192 + c_ * 512]); \
    }                                                                          \
  } while (0)

  auto compute = [&](int buf) {
    const unsigned short* As = &Sh[buf][0];
    const unsigned short* Bs = &Sh[buf][8192];
#pragma unroll
    for (int ks = 0; ks < 2; ks++) {
      const int cc = ks ? cs1 : cs0;
      short8 af[4], bf[4];
#pragma unroll
      for (int mt = 0; mt < 4; mt++)
        af[mt] = *(const short8*)&As[(wm + mt * 16 + lr) * 64 + cc];
#pragma unroll
      for (int nt = 0; nt < 4; nt++)
        bf[nt] = *(const short8*)&Bs[(wn + nt * 16 + lr) * 64 + cc];
#pragma unroll
      for (int mt = 0; mt < 4; mt++)
#pragma unroll
        for (int nt = 0; nt < 4; nt++)
          acc[mt][nt] = __builtin_amdgcn_mfma_f32_16x16x32_bf16(af[mt], bf[nt], acc[mt][nt], 0, 0, 0);
    }
  };

  GSTAGE(0, 0);
  for (int kb = 0; kb < DM / 64; kb += 2) {
    __syncthreads();                       // buf0 staged; prior buf0 readers done
    if (kb + 1 < DM / 64) GSTAGE(kb + 1, 1);
    compute(0);
    __syncthreads();                       // buf1 staged; prior buf1 readers done
    if (kb + 2 < DM / 64) GSTAGE(kb + 2, 0);
    compute(1);
  }
#undef GSTAGE

  if (mode == 1) {
    // ---- LDS transpose epilogue: Ts[n][m], stride 132 (conflict-free) ----
    unsigned short* Ts = &Sh[0][0];   // 16896 shorts, fits in 32768
    __syncthreads();   // all waves done reading Sh before overwrite
#pragma unroll
    for (int mt = 0; mt < 4; mt++) {
#pragma unroll
      for (int nt = 0; nt < 4; nt++) {
        int n = wn + nt * 16 + lr;
        int m = wm + mt * 16 + quad * 4;
        float bn = bias[n0 + n];
        alignas(8) unsigned short p4[4];
#pragma unroll
        for (int reg = 0; reg < 4; reg++)
          p4[reg] = f2b((acc[mt][nt][reg] + bn) * scale);
        *(uint2*)&Ts[n * 132 + m] = *(const uint2*)p4;
      }
    }
    __syncthreads();
    // copy out: thread t -> output row n = t>>1, m-half = (t&1)*64
    int n = t >> 1, mh = (t & 1) * 64;
    int gn = n0 + n;
    int h = gn >> 6, dk = gn & 63;
    int b = m0 >> 11, s0 = (m0 & (S_ - 1)) + mh;
    size_t obase = (size_t)((b * H_ + h) * 64 + dk) * S_ + s0;
#pragma unroll
    for (int c = 0; c < 8; c++)
      *(uint4*)&outb[obase + c * 8] = *(const uint4*)&Ts[n * 132 + mh + c * 8];
    return;
  }

  // epilogue (modes 0,2): C row = quad*4+reg, col = lr
#pragma unroll
  for (int mt = 0; mt < 4; mt++) {
#pragma unroll
    for (int nt = 0; nt < 4; nt++) {
#pragma unroll
      for (int reg = 0; reg < 4; reg++) {
        int gm = m0 + wm + mt * 16 + quad * 4 + reg;
        int gn = n0 + wn + nt * 16 + lr;
        float v = (acc[mt][nt][reg] + bias[gn]) * scale;
        if (mode == 0) {        // bf16 [B,H,S,DK]
          int b = gm >> 11, s = gm & (S_ - 1);
          int h = gn >> 6, dk = gn & 63;
          outb[(((size_t)(b * H_ + h) * S_ + s) << 6) + dk] = f2b(v);
        } else {                // fp32 [B*S, DM]
          outf[(size_t)gm * DM + gn] = v;
        }
      }
    }
  }
}

__global__ __launch_bounds__(256) void gemm_qkv_kernel(
    const unsigned short* __restrict__ xb, const unsigned short* __restrict__ wb,
    const float* __restrict__ bq, const float* __restrict__ bk, const float* __restrict__ bv,
    unsigned short* __restrict__ q_out, unsigned short* __restrict__ k_out,
    unsigned short* __restrict__ v_out) {
  int z = blockIdx.z;
  const unsigned short* A = xb + (size_t)z * (B_ * S_ * DM);
  const unsigned short* W = wb + (size_t)z * (DM * DM);
  const float* bias = (z == 0) ? bq : (z == 1) ? bk : bv;
  unsigned short* ob = (z == 0) ? q_out : (z == 1) ? k_out : v_out;
  gemm128(A, W, bias, (z == 0) ? QSCALE : 1.0f, (z == 2) ? 1 : 0, ob, nullptr);
}

__global__ __launch_bounds__(256) void gemm_out_kernel(
    const unsigned short* __restrict__ ab, const unsigned short* __restrict__ wb,
    const float* __restrict__ bo, float* __restrict__ out) {
  gemm128(ab, wb + (size_t)3 * (DM * DM), bo, 1.0f, 2, nullptr, out);
}

// ------- flash attention v7: swapped QK^T + in-register P via cvt_pk ------
// mfma(K, Q) puts keys on the C row axis: lane(lr,quad) holds
// P[key = nt*16 + quad*4 + r][q = mt*16 + lr].  cvt_pk packs adjacent key
// pairs; the preexpanded mask uint4 ANDs them (4 loads + 4 ANDs per (ks,mt)
// replacing the per-element shift/sext/and chain); permlane16_swap
// (D.r1<->S.r0, D.r3<->S.r2) then yields PV A-frags directly, in
// bit-reversed key-chunk order sigma(quad) = {0,2,1,3} -- V is consumed
// with sigma-permuted (still conflict-free swizzled) slots.
__global__ __launch_bounds__(256, 4) void attn_kernel(
    const unsigned short* __restrict__ qb, const unsigned short* __restrict__ kb,
    const unsigned short* __restrict__ vt, const uint4* __restrict__ em,
    unsigned short* __restrict__ ao) {
  __shared__ unsigned short Ks[2][64 * 64];  // slot sl of row r holds chunk sl^(r&7)
  __shared__ unsigned short Vs[2][64 * 64];  // same swizzle, rows are d
  const int bh = blockIdx.x;
  const int b = bh >> 4, h = bh & 15;
  const int t = threadIdx.x, lane = t & 63, wave = t >> 6;
  const int lr = lane & 15, quad = lane >> 4;
  const int q0 = blockIdx.y * 128 + wave * 32;  // wave owns 32 q-rows
  const unsigned short* qp = qb + (size_t)bh * S_ * DK;
  const unsigned short* kp = kb + (size_t)bh * S_ * DK;
  const unsigned short* vp = vt + (size_t)bh * DK * S_;
  // expanded-mask row: [b][g][kt][ks][mt][quad][lr], g = row group
  const int g = blockIdx.y * 4 + wave;
  const uint4* emrow = em + ((size_t)(b * 64 + g) * 32) * 256 + lane;

  // staging: thread -> (row 0..31, slot t&7), fetches global chunk (t&7)^(row&7)
  const int trow = t >> 3;
  const int tsw = ((t & 7) ^ (trow & 7)) * 8;
  const int wbase = wave * 512;              // shorts; HW appends lane*16B
  // K read-side swizzled chunk offsets (shorts): identity chunk order
  const int c0 = (quad ^ (lr & 7)) * 8;         // d 0..31
  const int c1 = ((4 + quad) ^ (lr & 7)) * 8;   // d 32..63
  // V read-side: bit-reversed chunk order to match permlane16_swap output
  const int brev = ((quad & 1) << 1) | (quad >> 1);
  const int vc0 = (brev ^ (lr & 7)) * 8;        // keys ks=0 (sigma order)
  const int vc1 = ((4 + brev) ^ (lr & 7)) * 8;  // keys ks=1

  short8 qf[2][2];
#pragma unroll
  for (int mt = 0; mt < 2; mt++)
#pragma unroll
    for (int ks = 0; ks < 2; ks++)
      qf[mt][ks] = *(const short8*)&qp[(size_t)(q0 + mt * 16 + lr) * DK + ks * 32 + quad * 8];

  const f32x4 zv = {0.f, 0.f, 0.f, 0.f};
  short8 ones;
#pragma unroll
  for (int i = 0; i < 8; i++) ones[i] = (short)0x3F80;  // bf16 1.0
  f32x4 oacc[2][4], lacc[2];
#pragma unroll
  for (int mt = 0; mt < 2; mt++) {
    lacc[mt] = zv;
#pragma unroll
    for (int nt = 0; nt < 4; nt++) oacc[mt][nt] = zv;
  }

#define STAGE(KT, BUF) do {                                                   \
    int kb2 = (KT) * 64;                                                      \
    gload_lds16(kp + (size_t)(kb2 + trow) * DK + tsw,      &Ks[BUF][wbase]);  \
    gload_lds16(kp + (size_t)(kb2 + 32 + trow) * DK + tsw, &Ks[BUF][2048 + wbase]); \
    gload_lds16(vp + (size_t)trow * S_ + kb2 + tsw,        &Vs[BUF][wbase]);  \
    gload_lds16(vp + (size_t)(32 + trow) * S_ + kb2 + tsw, &Vs[BUF][2048 + wbase]); \
  } while (0)

  auto body = [&](int kt, int buf) {
    // mask loads first: overlap with QK^T compute (4 x dwordx4, imm offsets)
    uint4 mm[2][2];
#pragma unroll
    for (int ks = 0; ks < 2; ks++)
#pragma unroll
      for (int mt = 0; mt < 2; mt++)
        mm[ks][mt] = emrow[(size_t)kt * 256 + (ks * 2 + mt) * 64];

#pragma unroll
    for (int ks = 0; ks < 2; ks++) {
      // ---- S^T = K Q^T for key tiles nt = 2ks, 2ks+1 (exp2 domain)
      f32x4 sc[2][2];  // [mt][ntl]
#pragma unroll
      for (int ntl = 0; ntl < 2; ntl++) {
        int nt = 2 * ks + ntl;
        short8 kf0 = *(const short8*)&Ks[buf][(nt * 16 + lr) * 64 + c0];
        short8 kf1 = *(const short8*)&Ks[buf][(nt * 16 + lr) * 64 + c1];
#pragma unroll
        for (int mt = 0; mt < 2; mt++) {
          f32x4 z = __builtin_amdgcn_mfma_f32_16x16x32_bf16(kf0, qf[mt][0], zv, 0, 0, 0);
          sc[mt][ntl] = __builtin_amdgcn_mfma_f32_16x16x32_bf16(kf1, qf[mt][1], z, 0, 0, 0);
        }
      }
      // ---- p = exp2(s) -> bf16 pairs; mask via preexpanded AND
      short8 pf[2];
#pragma unroll
      for (int mt = 0; mt < 2; mt++) {
        float pa[4], pb[4];
#pragma unroll
        for (int r = 0; r < 4; r++) {
          pa[r] = amd_exp2(sc[mt][0][r]);
          pb[r] = amd_exp2(sc[mt][1][r]);
        }
        unsigned int A0 = cvtpk_bf16(pa[0], pa[1]);
        unsigned int A1 = cvtpk_bf16(pa[2], pa[3]);
        unsigned int B0 = cvtpk_bf16(pb[0], pb[1]);
        unsigned int B1 = cvtpk_bf16(pb[2], pb[3]);
        const uint4 mv = mm[ks][mt];
        A0 &= mv.x; A1 &= mv.y; B0 &= mv.z; B1 &= mv.w;
        // D.r1<->S.r0, D.r3<->S.r2:
        //   A0 -> [A0r0,B0r0,A0r2,B0r2] = keys {0,1} of chunks {0,2,1,3}
        //   B0 -> [A0r1,B0r1,A0r3,B0r3] = keys {4,5} of chunks {0,2,1,3}
        asm("v_permlane16_swap_b32 %0, %1" : "+v"(A0), "+v"(B0));
        asm("v_permlane16_swap_b32 %0, %1" : "+v"(A1), "+v"(B1));
        union { unsigned int u[4]; short8 s8; } un;
        un.u[0] = A0; un.u[1] = A1; un.u[2] = B0; un.u[3] = B1;
        pf[mt] = un.s8;
      }
      // ---- l += P @ 1 (key order irrelevant)
#pragma unroll
      for (int mt = 0; mt < 2; mt++)
        lacc[mt] = __builtin_amdgcn_mfma_f32_16x16x32_bf16(pf[mt], ones, lacc[mt], 0, 0, 0);
      // ---- O += P V   (Vs rows are d; sigma-permuted key chunks)
      const int vc = ks ? vc1 : vc0;
#pragma unroll
      for (int nt = 0; nt < 4; nt++) {
        short8 vf = *(const short8*)&Vs[buf][(nt * 16 + lr) * 64 + vc];
#pragma unroll
        for (int mt = 0; mt < 2; mt++)
          oacc[mt][nt] = __builtin_amdgcn_mfma_f32_16x16x32_bf16(pf[mt], vf, oacc[mt][nt], 0, 0, 0);
      }
    }
  };

  STAGE(0, 0);
  for (int kt = 0; kt < S_ / 64; kt += 2) {
    __syncthreads();              // buf0 staged & prior readers of buf0 done
    STAGE(kt + 1, 1);             // prefetch next tile into buf1 (async)
    body(kt, 0);
    __syncthreads();              // buf1 staged & prior readers of buf1 done
    if (kt + 2 < S_ / 64) STAGE(kt + 2, 0);
    body(kt + 1, 1);
  }
#undef STAGE

  // ---- epilogue: O/l -> bf16 [B, S, H*DK]; fully-masked row -> 0
#pragma unroll
  for (int mt = 0; mt < 2; mt++) {
#pragma unroll
    for (int r = 0; r < 4; r++) {
      float l = lacc[mt][r];
      float inv = (l > 0.f) ? 1.f / l : 0.f;
      int row = q0 + mt * 16 + quad * 4 + r;
#pragma unroll
      for (int nt = 0; nt < 4; nt++)
        ao[((size_t)(b * S_ + row) * DM) + h * 64 + nt * 16 + lr] =
            f2b(oacc[mt][nt][r] * inv);
    }
  }
}

extern "C" void kernel_launch(void* const* d_in, const int* in_sizes, int n_in,
                              void* d_out, int out_size, void* d_ws, size_t ws_size,
                              hipStream_t stream) {
  const float* query = (const float*)d_in[0];
  const float* key   = (const float*)d_in[1];
  const float* value = (const float*)d_in[2];
  const int*   mask  = (const int*)d_in[3];
  const float* Wq = (const float*)d_in[4];
  const float* bq = (const float*)d_in[5];
  const float* Wk = (const float*)d_in[6];
  const float* bk = (const float*)d_in[7];
  const float* Wv = (const float*)d_in[8];
  const float* bv = (const float*)d_in[9];
  const float* Wo = (const float*)d_in[10];
  const float* bo = (const float*)d_in[11];
  float* out = (float*)d_out;
  char* ws = (char*)d_ws;

  // workspace layout (bytes)
  unsigned short* qb = (unsigned short*)(ws);                 // 16.78 MB [B,H,S,DK] (pre-scaled)
  unsigned short* kbf = (unsigned short*)(ws + 16777216);     // 16.78 MB [B,H,S,DK]
  unsigned short* vt = (unsigned short*)(ws + 33554432);      // 16.78 MB [B,H,DK,S]
  unsigned short* wb = (unsigned short*)(ws + 50331648);      // 8.39 MB  4x[DM,DM]
  unsigned short* xb = (unsigned short*)(ws + 58720256);      // 50.33 MB bf16 q,k,v inputs
  unsigned short* ao = (unsigned short*)(ws + 58720256);      // alias: q-input region, dead after QKV GEMM
  uint4* em = (uint4*)(ws + 75497472);                        // 33.55 MB expanded masks
                                                              // (aliases k/v bf16 inputs, dead after QKV GEMM)

  prep_kernel<<<dim3(14336), 256, 0, stream>>>(query, key, value, Wq, Wk, Wv, Wo, xb, wb);
  gemm_qkv_kernel<<<dim3(64, 8, 3), 256, 0, stream>>>(xb, wb, bq, bk, bv, qb, kbf, vt);
  expand_kernel<<<dim3(8192), 256, 0, stream>>>(mask, (uint4*)em);
  attn_kernel<<<dim3(64, 16), 256, 0, stream>>>(qb, kbf, vt, em, ao);
  gemm_out_kernel<<<dim3(64, 8), 256, 0, stream>>>(ao, wb, bo, out);
}

// Round 5
// 356.638 us; speedup vs baseline: 1.0777x; 1.0777x over previous
//
#include <hip/hip_runtime.h>

typedef __attribute__((ext_vector_type(8))) short short8;
typedef __attribute__((ext_vector_type(4))) float f32x4;

#define B_ 4
#define S_ 2048
#define H_ 16
#define DM 1024
#define DK 64

// 0.125 * log2(e): folds the 1/sqrt(64) score scale + exp->exp2 conversion into Q
#define QSCALE 0.18033688011112042f

__device__ __forceinline__ unsigned short f2b(float f) {
  unsigned int u = __float_as_uint(f);
  u += 0x7fff + ((u >> 16) & 1);   // RNE
  return (unsigned short)(u >> 16);
}

__device__ __forceinline__ unsigned int cvtpk_bf16(float lo, float hi) {
  unsigned int r;
  asm("v_cvt_pk_bf16_f32 %0, %1, %2" : "=v"(r) : "v"(lo), "v"(hi));
  return r;
}

// native exp2 without OCML's denorm-guard fixup (scores are |s| < ~30 here)
__device__ __forceinline__ float amd_exp2(float x) {
#if __has_builtin(__builtin_amdgcn_exp2f)
  return __builtin_amdgcn_exp2f(x);
#else
  return exp2f(x);
#endif
}

__device__ __forceinline__ void gload_lds16(const void* g, void* l) {
  __builtin_amdgcn_global_load_lds(
      (const __attribute__((address_space(1))) unsigned int*)g,
      (__attribute__((address_space(3))) unsigned int*)l, 16, 0, 0);
}

// ------- fused fp32 -> bf16 conversion for x(q,k,v) and W(q,k,v,o) -------
// one launch: blocks [0,12288) convert inputs, [12288,14336) convert weights
__global__ __launch_bounds__(256) void prep_kernel(
    const float* __restrict__ q, const float* __restrict__ k,
    const float* __restrict__ v, const float* __restrict__ wq,
    const float* __restrict__ wk, const float* __restrict__ wv,
    const float* __restrict__ wo, unsigned short* __restrict__ xb,
    unsigned short* __restrict__ wbo) {
  int bid = blockIdx.x;
  const float* src;
  unsigned short* dst;
  int i;
  if (bid < 12288) {
    int z = bid >> 12;                    // 4096 blocks per tensor
    src = (z == 0) ? q : (z == 1) ? k : v;
    dst = xb + (size_t)z * (B_ * S_ * DM);
    i = ((bid & 4095) * 256 + threadIdx.x) * 8;
  } else {
    int r = bid - 12288;
    int z = r >> 9;                       // 512 blocks per weight
    src = (z == 0) ? wq : (z == 1) ? wk : (z == 2) ? wv : wo;
    dst = wbo + (size_t)z * (DM * DM);
    i = ((r & 511) * 256 + threadIdx.x) * 8;
  }
  float4 x0 = *(const float4*)&src[i];
  float4 x1 = *(const float4*)&src[i + 4];
  alignas(16) unsigned short r8[8] = {f2b(x0.x), f2b(x0.y), f2b(x0.z), f2b(x0.w),
                                      f2b(x1.x), f2b(x1.y), f2b(x1.z), f2b(x1.w)};
  *(uint4*)&dst[i] = *(const uint4*)r8;
}

// -------- mask (int32 0/1) -> expanded packed-pair masks -----------------
// Output layout [b][g][kt][ks][mt][quad][lr] (uint4), g = q>>5 (row group),
// mt = (q>>4)&1, lr = q&15.  The uint4 {A0m,A1m,B0m,B1m} is exactly the
// halfword mask for the cvt_pk-packed P pairs in attn:
//   A0m: keys kb+quad*4+{0(lo),1(hi)}   A1m: +{2,3}     (kb = kt*64+ks*32)
//   B0m: keys kb+16+quad*4+{0,1}        B1m: +{2,3}
__global__ __launch_bounds__(256) void expand_kernel(const int* __restrict__ m,
                                                     uint4* __restrict__ out) {
  unsigned int t = blockIdx.x * 256 + threadIdx.x;   // 0 .. 2^21-1
  int lr   = t & 15;
  int quad = (t >> 4) & 3;
  int mt   = (t >> 6) & 1;
  int ks   = (t >> 7) & 1;
  int kt   = (t >> 8) & 31;
  int g    = (t >> 13) & 63;
  int b    = t >> 19;
  int q = g * 32 + mt * 16 + lr;
  int kbase = kt * 64 + ks * 32 + quad * 4;
  const int* row = m + (((size_t)(b * 2048 + q)) << 11) + kbase;
  int4 m0 = *(const int4*)row;          // keys kbase..+3
  int4 m1 = *(const int4*)(row + 16);   // keys kbase+16..+19
  uint4 r;
  r.x = (m0.x ? 0xFFFFu : 0u) | (m0.y ? 0xFFFF0000u : 0u);
  r.y = (m0.z ? 0xFFFFu : 0u) | (m0.w ? 0xFFFF0000u : 0u);
  r.z = (m1.x ? 0xFFFFu : 0u) | (m1.y ? 0xFFFF0000u : 0u);
  r.w = (m1.z ? 0xFFFFu : 0u) | (m1.w ? 0xFFFF0000u : 0u);
  out[t] = r;
}

// ---------- 128x128 bf16 GEMM, counted-vmcnt double-buffer (T3/T4) --------
// LDS slot sl of row r holds global 16B-chunk sl^(r&7) (3-bit chunk swizzle).
// Raw s_barrier + hand-counted s_waitcnt: tile t lives in buf[t&1]; per iter:
//   vmcnt(8)  -> tile t landed (tile t+1's 8 loads stay IN FLIGHT)
//   barrier   -> all waves' tile-t loads landed
//   compute(t)
//   lgkmcnt(0); barrier -> all waves' reads of buf[t&1] done
//   STAGE(t+2 -> buf[t&1])   (issued ~2 iters before needed: hides HBM)
// No vmcnt(0) drain in the steady loop (the __syncthreads structural stall).
// mode 1 (V^T output) routes the tile through an LDS transpose so global
// stores are coalesced dwordx4 runs along s.
__device__ __forceinline__ void gemm128(
    const unsigned short* __restrict__ A, const unsigned short* __restrict__ W,
    const float* __restrict__ bias, float scale, int mode,
    unsigned short* __restrict__ outb, float* __restrict__ outf) {
  __shared__ unsigned short Sh[2][16384];  // [buf][ As(8192) | Bs(8192) ]  64 KB
  const int m0 = blockIdx.x * 128;
  const int n0 = blockIdx.y * 128;
  const int t = threadIdx.x;
  const int lane = t & 63, wave = t >> 6;
  const int lr = lane & 15, quad = lane >> 4;
  const int wm = (wave >> 1) * 64, wn = (wave & 1) * 64;
  const int srow = (lane >> 3);               // within-chunk row 0..7
  const int scol = ((lane & 7) ^ srow) * 8;   // swizzled global col chunk
  // read-side swizzled chunk offsets (shorts), per-lane invariant
  const int cs0 = (quad ^ (lr & 7)) * 8;        // ks=0
  const int cs1 = ((4 + quad) ^ (lr & 7)) * 8;  // ks=1

  const f32x4 zv = {0.f, 0.f, 0.f, 0.f};
  f32x4 acc[4][4];
#pragma unroll
  for (int mt = 0; mt < 4; mt++)
#pragma unroll
    for (int nt = 0; nt < 4; nt++) acc[mt][nt] = zv;

#define GSTAGE(KB, BUF) do {                                                   \
    int kb2 = (KB) * 64;                                                       \
    _Pragma("unroll")                                                          \
    for (int i_ = 0; i_ < 4; i_++) {                                           \
      int c_ = wave * 4 + i_;            /* chunk of 8 rows (1 KB) */          \
      int row_ = c_ * 8 + srow;                                                \
      gload_lds16(&A[(size_t)(m0 + row_) * DM + kb2 + scol], &Sh[BUF][c_ * 512]); \
      gload_lds16(&W[(size_t)(n0 + row_) * DM + kb2 + scol], &Sh[BUF][8192 + c_ * 512]); \
    }                                                                          \
  } while (0)

  auto compute = [&](int buf) {
    const unsigned short* As = &Sh[buf][0];
    const unsigned short* Bs = &Sh[buf][8192];
#pragma unroll
    for (int ks = 0; ks < 2; ks++) {
      const int cc = ks ? cs1 : cs0;
      short8 af[4], bf[4];
#pragma unroll
      for (int mt = 0; mt < 4; mt++)
        af[mt] = *(const short8*)&As[(wm + mt * 16 + lr) * 64 + cc];
#pragma unroll
      for (int nt = 0; nt < 4; nt++)
        bf[nt] = *(const short8*)&Bs[(wn + nt * 16 + lr) * 64 + cc];
#pragma unroll
      for (int mt = 0; mt < 4; mt++)
#pragma unroll
        for (int nt = 0; nt < 4; nt++)
          acc[mt][nt] = __builtin_amdgcn_mfma_f32_16x16x32_bf16(af[mt], bf[nt], acc[mt][nt], 0, 0, 0);
    }
  };

  // prologue: tiles 0 and 1 in flight
  GSTAGE(0, 0);
  GSTAGE(1, 1);
  // steady loop: kb = 0..13 (DM/64 = 16 tiles total)
  for (int kb = 0; kb < DM / 64 - 2; kb++) {
    asm volatile("s_waitcnt vmcnt(8)" ::: "memory");   // tile kb landed
    __builtin_amdgcn_s_barrier();                      // ...for ALL waves
    compute(kb & 1);
    asm volatile("s_waitcnt lgkmcnt(0)" ::: "memory"); // my reads retired
    __builtin_amdgcn_s_barrier();                      // everyone's reads retired
    GSTAGE(kb + 2, kb & 1);                            // overwrite freed buffer
  }
  // kb = 14: tile 15's 8 loads still outstanding
  asm volatile("s_waitcnt vmcnt(8)" ::: "memory");
  __builtin_amdgcn_s_barrier();
  compute(0);
  // kb = 15: wait everything, no staging follows
  asm volatile("s_waitcnt vmcnt(0)" ::: "memory");
  __builtin_amdgcn_s_barrier();
  compute(1);

  if (mode == 1) {
    // ---- LDS transpose epilogue: Ts[n][m], stride 132 (conflict-free) ----
    unsigned short* Ts = &Sh[0][0];   // 16896 shorts, fits in 65536 B
    __syncthreads();   // all waves done reading Sh before overwrite
#pragma unroll
    for (int mt = 0; mt < 4; mt++) {
#pragma unroll
      for (int nt = 0; nt < 4; nt++) {
        int n = wn + nt * 16 + lr;
        int m = wm + mt * 16 + quad * 4;
        float bn = bias[n0 + n];
        alignas(8) unsigned short p4[4];
#pragma unroll
        for (int reg = 0; reg < 4; reg++)
          p4[reg] = f2b((acc[mt][nt][reg] + bn) * scale);
        *(uint2*)&Ts[n * 132 + m] = *(const uint2*)p4;
      }
    }
    __syncthreads();
    // copy out: thread t -> output row n = t>>1, m-half = (t&1)*64
    int n = t >> 1, mh = (t & 1) * 64;
    int gn = n0 + n;
    int h = gn >> 6, dk = gn & 63;
    int b = m0 >> 11, s0 = (m0 & (S_ - 1)) + mh;
    size_t obase = (size_t)((b * H_ + h) * 64 + dk) * S_ + s0;
#pragma unroll
    for (int c = 0; c < 8; c++)
      *(uint4*)&outb[obase + c * 8] = *(const uint4*)&Ts[n * 132 + mh + c * 8];
    return;
  }

  // epilogue (modes 0,2): C row = quad*4+reg, col = lr
#pragma unroll
  for (int mt = 0; mt < 4; mt++) {
#pragma unroll
    for (int nt = 0; nt < 4; nt++) {
#pragma unroll
      for (int reg = 0; reg < 4; reg++) {
        int gm = m0 + wm + mt * 16 + quad * 4 + reg;
        int gn = n0 + wn + nt * 16 + lr;
        float v = (acc[mt][nt][reg] + bias[gn]) * scale;
        if (mode == 0) {        // bf16 [B,H,S,DK]
          int b = gm >> 11, s = gm & (S_ - 1);
          int h = gn >> 6, dk = gn & 63;
          outb[(((size_t)(b * H_ + h) * S_ + s) << 6) + dk] = f2b(v);
        } else {                // fp32 [B*S, DM]
          outf[(size_t)gm * DM + gn] = v;
        }
      }
    }
  }
#undef GSTAGE
}

__global__ __launch_bounds__(256) void gemm_qkv_kernel(
    const unsigned short* __restrict__ xb, const unsigned short* __restrict__ wb,
    const float* __restrict__ bq, const float* __restrict__ bk, const float* __restrict__ bv,
    unsigned short* __restrict__ q_out, unsigned short* __restrict__ k_out,
    unsigned short* __restrict__ v_out) {
  int z = blockIdx.z;
  const unsigned short* A = xb + (size_t)z * (B_ * S_ * DM);
  const unsigned short* W = wb + (size_t)z * (DM * DM);
  const float* bias = (z == 0) ? bq : (z == 1) ? bk : bv;
  unsigned short* ob = (z == 0) ? q_out : (z == 1) ? k_out : v_out;
  gemm128(A, W, bias, (z == 0) ? QSCALE : 1.0f, (z == 2) ? 1 : 0, ob, nullptr);
}

__global__ __launch_bounds__(256) void gemm_out_kernel(
    const unsigned short* __restrict__ ab, const unsigned short* __restrict__ wb,
    const float* __restrict__ bo, float* __restrict__ out) {
  gemm128(ab, wb + (size_t)3 * (DM * DM), bo, 1.0f, 2, nullptr, out);
}

// ------- flash attention v8: v7 + s_setprio(1) around MFMA clusters -------
// mfma(K, Q) puts keys on the C row axis: lane(lr,quad) holds
// P[key = nt*16 + quad*4 + r][q = mt*16 + lr].  cvt_pk packs adjacent key
// pairs; the preexpanded mask uint4 ANDs them; permlane16_swap
// (D.r1<->S.r0, D.r3<->S.r2) then yields PV A-frags directly, in
// bit-reversed key-chunk order sigma(quad) = {0,2,1,3} -- V is consumed
// with sigma-permuted (still conflict-free swizzled) slots.
// Each SIMD hosts 4 waves of 4 DIFFERENT blocks (independently phased):
// setprio favors the wave in its MFMA cluster over waves issuing loads.
__global__ __launch_bounds__(256, 4) void attn_kernel(
    const unsigned short* __restrict__ qb, const unsigned short* __restrict__ kb,
    const unsigned short* __restrict__ vt, const uint4* __restrict__ em,
    unsigned short* __restrict__ ao) {
  __shared__ unsigned short Ks[2][64 * 64];  // slot sl of row r holds chunk sl^(r&7)
  __shared__ unsigned short Vs[2][64 * 64];  // same swizzle, rows are d
  const int bh = blockIdx.x;
  const int b = bh >> 4, h = bh & 15;
  const int t = threadIdx.x, lane = t & 63, wave = t >> 6;
  const int lr = lane & 15, quad = lane >> 4;
  const int q0 = blockIdx.y * 128 + wave * 32;  // wave owns 32 q-rows
  const unsigned short* qp = qb + (size_t)bh * S_ * DK;
  const unsigned short* kp = kb + (size_t)bh * S_ * DK;
  const unsigned short* vp = vt + (size_t)bh * DK * S_;
  // expanded-mask row: [b][g][kt][ks][mt][quad][lr], g = row group
  const int g = blockIdx.y * 4 + wave;
  const uint4* emrow = em + ((size_t)(b * 64 + g) * 32) * 256 + lane;

  // staging: thread -> (row 0..31, slot t&7), fetches global chunk (t&7)^(row&7)
  const int trow = t >> 3;
  const int tsw = ((t & 7) ^ (trow & 7)) * 8;
  const int wbase = wave * 512;              // shorts; HW appends lane*16B
  // K read-side swizzled chunk offsets (shorts): identity chunk order
  const int c0 = (quad ^ (lr & 7)) * 8;         // d 0..31
  const int c1 = ((4 + quad) ^ (lr & 7)) * 8;   // d 32..63
  // V read-side: bit-reversed chunk order to match permlane16_swap output
  const int brev = ((quad & 1) << 1) | (quad >> 1);
  const int vc0 = (brev ^ (lr & 7)) * 8;        // keys ks=0 (sigma order)
  const int vc1 = ((4 + brev) ^ (lr & 7)) * 8;  // keys ks=1

  short8 qf[2][2];
#pragma unroll
  for (int mt = 0; mt < 2; mt++)
#pragma unroll
    for (int ks = 0; ks < 2; ks++)
      qf[mt][ks] = *(const short8*)&qp[(size_t)(q0 + mt * 16 + lr) * DK + ks * 32 + quad * 8];

  const f32x4 zv = {0.f, 0.f, 0.f, 0.f};
  short8 ones;
#pragma unroll
  for (int i = 0; i < 8; i++) ones[i] = (short)0x3F80;  // bf16 1.0
  f32x4 oacc[2][4], lacc[2];
#pragma unroll
  for (int mt = 0; mt < 2; mt++) {
    lacc[mt] = zv;
#pragma unroll
    for (int nt = 0; nt < 4; nt++) oacc[mt][nt] = zv;
  }

#define STAGE(KT, BUF) do {                                                   \
    int kb2 = (KT) * 64;                                                      \
    gload_lds16(kp + (size_t)(kb2 + trow) * DK + tsw,      &Ks[BUF][wbase]);  \
    gload_lds16(kp + (size_t)(kb2 + 32 + trow) * DK + tsw, &Ks[BUF][2048 + wbase]); \
    gload_lds16(vp + (size_t)trow * S_ + kb2 + tsw,        &Vs[BUF][wbase]);  \
    gload_lds16(vp + (size_t)(32 + trow) * S_ + kb2 + tsw, &Vs[BUF][2048 + wbase]); \
  } while (0)

  auto body = [&](int kt, int buf) {
    // mask loads first: overlap with QK^T compute (4 x dwordx4, imm offsets)
    uint4 mm[2][2];
#pragma unroll
    for (int ks = 0; ks < 2; ks++)
#pragma unroll
      for (int mt = 0; mt < 2; mt++)
        mm[ks][mt] = emrow[(size_t)kt * 256 + (ks * 2 + mt) * 64];

#pragma unroll
    for (int ks = 0; ks < 2; ks++) {
      // ---- S^T = K Q^T for key tiles nt = 2ks, 2ks+1 (exp2 domain)
      f32x4 sc[2][2];  // [mt][ntl]
      __builtin_amdgcn_s_setprio(1);
#pragma unroll
      for (int ntl = 0; ntl < 2; ntl++) {
        int nt = 2 * ks + ntl;
        short8 kf0 = *(const short8*)&Ks[buf][(nt * 16 + lr) * 64 + c0];
        short8 kf1 = *(const short8*)&Ks[buf][(nt * 16 + lr) * 64 + c1];
#pragma unroll
        for (int mt = 0; mt < 2; mt++) {
          f32x4 z = __builtin_amdgcn_mfma_f32_16x16x32_bf16(kf0, qf[mt][0], zv, 0, 0, 0);
          sc[mt][ntl] = __builtin_amdgcn_mfma_f32_16x16x32_bf16(kf1, qf[mt][1], z, 0, 0, 0);
        }
      }
      __builtin_amdgcn_s_setprio(0);
      // ---- p = exp2(s) -> bf16 pairs; mask via preexpanded AND
      short8 pf[2];
#pragma unroll
      for (int mt = 0; mt < 2; mt++) {
        float pa[4], pb[4];
#pragma unroll
        for (int r = 0; r < 4; r++) {
          pa[r] = amd_exp2(sc[mt][0][r]);
          pb[r] = amd_exp2(sc[mt][1][r]);
        }
        unsigned int A0 = cvtpk_bf16(pa[0], pa[1]);
        unsigned int A1 = cvtpk_bf16(pa[2], pa[3]);
        unsigned int B0 = cvtpk_bf16(pb[0], pb[1]);
        unsigned int B1 = cvtpk_bf16(pb[2], pb[3]);
        const uint4 mv = mm[ks][mt];
        A0 &= mv.x; A1 &= mv.y; B0 &= mv.z; B1 &= mv.w;
        // D.r1<->S.r0, D.r3<->S.r2:
        //   A0 -> [A0r0,B0r0,A0r2,B0r2] = keys {0,1} of chunks {0,2,1,3}
        //   B0 -> [A0r1,B0r1,A0r3,B0r3] = keys {4,5} of chunks {0,2,1,3}
        asm("v_permlane16_swap_b32 %0, %1" : "+v"(A0), "+v"(B0));
        asm("v_permlane16_swap_b32 %0, %1" : "+v"(A1), "+v"(B1));
        union { unsigned int u[4]; short8 s8; } un;
        un.u[0] = A0; un.u[1] = A1; un.u[2] = B0; un.u[3] = B1;
        pf[mt] = un.s8;
      }
      // ---- l += P @ 1 ; O += P V   (Vs rows are d; sigma-permuted chunks)
      __builtin_amdgcn_s_setprio(1);
#pragma unroll
      for (int mt = 0; mt < 2; mt++)
        lacc[mt] = __builtin_amdgcn_mfma_f32_16x16x32_bf16(pf[mt], ones, lacc[mt], 0, 0, 0);
      const int vc = ks ? vc1 : vc0;
#pragma unroll
      for (int nt = 0; nt < 4; nt++) {
        short8 vf = *(const short8*)&Vs[buf][(nt * 16 + lr) * 64 + vc];
#pragma unroll
        for (int mt = 0; mt < 2; mt++)
          oacc[mt][nt] = __builtin_amdgcn_mfma_f32_16x16x32_bf16(pf[mt], vf, oacc[mt][nt], 0, 0, 0);
      }
      __builtin_amdgcn_s_setprio(0);
    }
  };

  STAGE(0, 0);
  for (int kt = 0; kt < S_ / 64; kt += 2) {
    __syncthreads();              // buf0 staged & prior readers of buf0 done
    STAGE(kt + 1, 1);             // prefetch next tile into buf1 (async)
    body(kt, 0);
    __syncthreads();              // buf1 staged & prior readers of buf1 done
    if (kt + 2 < S_ / 64) STAGE(kt + 2, 0);
    body(kt + 1, 1);
  }
#undef STAGE

  // ---- epilogue: O/l -> bf16 [B, S, H*DK]; fully-masked row -> 0
#pragma unroll
  for (int mt = 0; mt < 2; mt++) {
#pragma unroll
    for (int r = 0; r < 4; r++) {
      float l = lacc[mt][r];
      float inv = (l > 0.f) ? 1.f / l : 0.f;
      int row = q0 + mt * 16 + quad * 4 + r;
#pragma unroll
      for (int nt = 0; nt < 4; nt++)
        ao[((size_t)(b * S_ + row) * DM) + h * 64 + nt * 16 + lr] =
            f2b(oacc[mt][nt][r] * inv);
    }
  }
}

extern "C" void kernel_launch(void* const* d_in, const int* in_sizes, int n_in,
                              void* d_out, int out_size, void* d_ws, size_t ws_size,
                              hipStream_t stream) {
  const float* query = (const float*)d_in[0];
  const float* key   = (const float*)d_in[1];
  const float* value = (const float*)d_in[2];
  const int*   mask  = (const int*)d_in[3];
  const float* Wq = (const float*)d_in[4];
  const float* bq = (const float*)d_in[5];
  const float* Wk = (const float*)d_in[6];
  const float* bk = (const float*)d_in[7];
  const float* Wv = (const float*)d_in[8];
  const float* bv = (const float*)d_in[9];
  const float* Wo = (const float*)d_in[10];
  const float* bo = (const float*)d_in[11];
  float* out = (float*)d_out;
  char* ws = (char*)d_ws;

  // workspace layout (bytes)
  unsigned short* qb = (unsigned short*)(ws);                 // 16.78 MB [B,H,S,DK] (pre-scaled)
  unsigned short* kbf = (unsigned short*)(ws + 16777216);     // 16.78 MB [B,H,S,DK]
  unsigned short* vt = (unsigned short*)(ws + 33554432);      // 16.78 MB [B,H,DK,S]
  unsigned short* wb = (unsigned short*)(ws + 50331648);      // 8.39 MB  4x[DM,DM]
  unsigned short* xb = (unsigned short*)(ws + 58720256);      // 50.33 MB bf16 q,k,v inputs
  unsigned short* ao = (unsigned short*)(ws + 58720256);      // alias: q-input region, dead after QKV GEMM
  uint4* em = (uint4*)(ws + 75497472);                        // 33.55 MB expanded masks
                                                              // (aliases k/v bf16 inputs, dead after QKV GEMM)

  prep_kernel<<<dim3(14336), 256, 0, stream>>>(query, key, value, Wq, Wk, Wv, Wo, xb, wb);
  gemm_qkv_kernel<<<dim3(64, 8, 3), 256, 0, stream>>>(xb, wb, bq, bk, bv, qb, kbf, vt);
  expand_kernel<<<dim3(8192), 256, 0, stream>>>(mask, (uint4*)em);
  attn_kernel<<<dim3(64, 16), 256, 0, stream>>>(qb, kbf, vt, em, ao);
  gemm_out_kernel<<<dim3(64, 8), 256, 0, stream>>>(ao, wb, bo, out);
}